// Round 6
// baseline (694.577 us; speedup 1.0000x reference)
//
#include <hip/hip_runtime.h>
#include <math.h>

// Problem constants (from reference): B=4, L=4096, D=1024
#define B_SZ 4
#define L_SZ 4096
#define D_SZ 1024
#define M_SZ (B_SZ * L_SZ)      // 16384 tokens
#define NBINS 513               // rfft bins for D=1024
#define CCH   (2 * NBINS)       // 1026 float channels per token (interleaved re,im)
#define TCH 32                  // cumsum chunks over L
#define TLEN (L_SZ / TCH)       // 128 timesteps per chunk

typedef short bf16x8 __attribute__((ext_vector_type(8)));
typedef float f32x4  __attribute__((ext_vector_type(4)));
typedef unsigned short us8 __attribute__((ext_vector_type(8)));

// round-to-nearest-even f32 -> bf16
__device__ inline unsigned short f2bf(float f) {
    unsigned int u = __float_as_uint(f);
    u += 0x7fffu + ((u >> 16) & 1u);
    return (unsigned short)(u >> 16);
}

// ---------------------------------------------------------------------------
// f32 -> bf16 cast, 8 elements/thread
// ---------------------------------------------------------------------------
__global__ __launch_bounds__(256) void cast_f32_bf16(
        const float* __restrict__ in, unsigned short* __restrict__ out, int n8) {
    int i = blockIdx.x * 256 + threadIdx.x;
    if (i >= n8) return;
    const float4* p = (const float4*)in + 2 * (size_t)i;
    float4 a = p[0], b = p[1];
    us8 o;
    o[0] = f2bf(a.x); o[1] = f2bf(a.y); o[2] = f2bf(a.z); o[3] = f2bf(a.w);
    o[4] = f2bf(b.x); o[5] = f2bf(b.y); o[6] = f2bf(b.z); o[7] = f2bf(b.w);
    *(us8*)(out + (size_t)i * 8) = o;
}

// ---------------------------------------------------------------------------
// bf16 MFMA GEMM, LDS-FREE: both operand fragments load straight from global
// (L2-resident via XCD swizzle) into VGPRs. No __syncthreads in the K-loop,
// so the compiler software-pipelines loads across iterations (per-use vmcnt)
// instead of the m97 barrier-drain structure (which stalled at ~10-22%
// MfmaUtil for K=1024).
//
// A: M x K bf16.  W: (CN*128) x K bf16 (torch Linear layout).  K = 1024.
// Logical N split in halves of 1024: cols [0,1024)->C0/bias0, [1024,2048)->
// C1/bias1 (fused K+V projection). resid (fp32 M x 1024) added if non-null.
//
// Swizzle: id -> bx=(id>>3)%CN, by=(id&7)+8*(id/(8*CN)): blocks sharing an A
// row-tile land on one XCD; per-XCD A working set fits the 4 MB L2.
// ---------------------------------------------------------------------------
#define GBM 128
#define GBN 128
template<int CN>
__global__ __launch_bounds__(256) void gemm_mfma(
        const unsigned short* __restrict__ A, const unsigned short* __restrict__ W,
        const float* __restrict__ bias0, const float* __restrict__ bias1,
        const float* __restrict__ resid,
        float* __restrict__ C0, float* __restrict__ C1, int M, int K) {
    const int id   = blockIdx.x;
    const int bx   = (id >> 3) % CN;
    const int by   = (id & 7) + 8 * (id / (8 * CN));
    const int tid  = threadIdx.x;
    const int lane = tid & 63;
    const int wave = tid >> 6;                 // 0..3
    const int wm   = wave & 1;
    const int wn   = wave >> 1;
    const int bm   = by * GBM;
    const int bn   = bx * GBN;

    f32x4 acc[4][4] = {};

    const int fr = lane & 15;          // fragment row (m or n within 16)
    const int fk = (lane >> 4) * 8;    // fragment k-offset

    // per-thread fragment base pointers (16B-aligned: K even, fk*2 mult of 16)
    const unsigned short* pa[4];
    const unsigned short* pw[4];
    #pragma unroll
    for (int t = 0; t < 4; t++) {
        pa[t] = A + (size_t)(bm + wm * 64 + t * 16 + fr) * K + fk;
        pw[t] = W + (size_t)(bn + wn * 64 + t * 16 + fr) * K + fk;
    }

    #pragma unroll 2
    for (int k0 = 0; k0 < K; k0 += 32) {
        bf16x8 af[4], bfr[4];
        #pragma unroll
        for (int t = 0; t < 4; t++) {
            af[t]  = *(const bf16x8*)(pa[t] + k0);
            bfr[t] = *(const bf16x8*)(pw[t] + k0);
        }
        #pragma unroll
        for (int i = 0; i < 4; i++)
            #pragma unroll
            for (int j = 0; j < 4; j++)
                acc[i][j] = __builtin_amdgcn_mfma_f32_16x16x32_bf16(
                                af[i], bfr[j], acc[i][j], 0, 0, 0);
    }

    // epilogue: C/D layout col=lane&15, row=(lane>>4)*4+reg
    const int col0 = lane & 15;
    const int quad = lane >> 4;
    #pragma unroll
    for (int j = 0; j < 4; j++) {
        const int ng = bn + wn * 64 + j * 16 + col0;   // global col in [0, CN*128)
        const int half = ng >> 10;                     // 0 or 1 (uniform per j)
        const int n = ng & 1023;
        float* __restrict__ Cp = half ? C1 : C0;
        const float bv = half ? bias1[n] : bias0[n];
        #pragma unroll
        for (int i = 0; i < 4; i++) {
            #pragma unroll
            for (int r = 0; r < 4; r++) {
                const int m = bm + wm * 64 + i * 16 + quad * 4 + r;
                float v = acc[i][j][r] + bv;
                size_t off = (size_t)m * 1024 + n;
                if (resid) v += resid[off];
                Cp[off] = v;
            }
        }
    }
}

// ---------------------------------------------------------------------------
// Stockham radix-4 1024-pt FFT. 256 threads, 4 complex/thread in registers,
// 5 stages, exchanges via two swizzled float2 LDS buffers (conflict-free).
// ---------------------------------------------------------------------------
#define SWZ(a) ((a) ^ (((a) >> 4) & 15))

struct cplx { float r, i; };
__device__ inline cplx cmul(cplx a, cplx b) {
    return {a.r * b.r - a.i * b.i, a.r * b.i + a.i * b.r};
}

__device__ inline void r4bfly(cplx v[4], float s) {
    cplx t0 {v[0].r + v[2].r, v[0].i + v[2].i};
    cplx t1 {v[0].r - v[2].r, v[0].i - v[2].i};
    cplx t2 {v[1].r + v[3].r, v[1].i + v[3].i};
    cplx t3 {v[1].r - v[3].r, v[1].i - v[3].i};
    cplx j3 {-s * t3.i, s * t3.r};     // s*i * t3
    v[0] = {t0.r + t2.r, t0.i + t2.i};
    v[2] = {t0.r - t2.r, t0.i - t2.i};
    v[1] = {t1.r + j3.r, t1.i + j3.i};
    v[3] = {t1.r - j3.r, t1.i - j3.i};
}

template<int SIGN>
__device__ inline void fft1024_r(float2* bA, float2* bB, cplx v[4], int tid) {
    const float s = (float)SIGN;
    r4bfly(v, s);
    {
        const int base = tid << 2;
        #pragma unroll
        for (int e = 0; e < 4; e++)
            bA[SWZ(base + e)] = make_float2(v[e].r, v[e].i);
    }
    __syncthreads();
    float2* cur = bA;
    float2* nxt = bB;
    #pragma unroll
    for (int q = 1; q <= 3; q++) {
        const int Ls = 1 << (2 * q);
        #pragma unroll
        for (int k = 0; k < 4; k++) {
            float2 t = cur[SWZ(tid + (k << 8))];
            v[k] = {t.x, t.y};
        }
        const int d = tid & (Ls - 1);
        const float ang = s * 1.57079632679489662f * (float)d / (float)Ls;
        float sn, cs; __sincosf(ang, &sn, &cs);
        cplx w1 {cs, sn};
        cplx w2 = cmul(w1, w1);
        cplx w3 = cmul(w2, w1);
        v[1] = cmul(v[1], w1);
        v[2] = cmul(v[2], w2);
        v[3] = cmul(v[3], w3);
        r4bfly(v, s);
        const int base = ((tid >> (2 * q)) << (2 * q + 2)) + d;
        #pragma unroll
        for (int e = 0; e < 4; e++)
            nxt[SWZ(base + (e << (2 * q)))] = make_float2(v[e].r, v[e].i);
        float2* tmp = cur; cur = nxt; nxt = tmp;
        __syncthreads();
    }
    #pragma unroll
    for (int k = 0; k < 4; k++) {
        float2 t = cur[SWZ(tid + (k << 8))];
        v[k] = {t.x, t.y};
    }
    {
        const float ang = s * 1.57079632679489662f * (float)tid / 256.0f;
        float sn, cs; __sincosf(ang, &sn, &cs);
        cplx w1 {cs, sn};
        cplx w2 = cmul(w1, w1);
        cplx w3 = cmul(w2, w1);
        v[1] = cmul(v[1], w1);
        v[2] = cmul(v[2], w2);
        v[3] = cmul(v[3], w3);
        r4bfly(v, s);
    }
}

// ---------------------------------------------------------------------------
// Bind: normalize keys, pack z = k_hat + i*v, one forward FFT, unpack the two
// real-signal spectra (Kf even part, Vf odd part), write P = Kf*Vf.
// ---------------------------------------------------------------------------
__global__ __launch_bounds__(256) void bind_fft_kernel(
        const float* __restrict__ Kraw, const float* __restrict__ V,
        float* __restrict__ P) {
    __shared__ float2 bA[1024], bB[1024];
    __shared__ float red[256];
    const int token = blockIdx.x;
    const int tid = threadIdx.x;

    const float* krow = Kraw + (size_t)token * D_SZ;
    const float* vrow = V    + (size_t)token * D_SZ;
    float kv[4], vv[4];
    float ss = 0.0f;
    #pragma unroll
    for (int k = 0; k < 4; k++) {
        kv[k] = krow[tid + (k << 8)];
        vv[k] = vrow[tid + (k << 8)];
        ss += kv[k] * kv[k];
    }
    red[tid] = ss;
    __syncthreads();
    for (int sft = 128; sft > 0; sft >>= 1) {
        if (tid < sft) red[tid] += red[tid + sft];
        __syncthreads();
    }
    const float scale = 1.0f / fmaxf(sqrtf(red[0]), 1e-12f);

    cplx z[4];
    #pragma unroll
    for (int k = 0; k < 4; k++) z[k] = {kv[k] * scale, vv[k]};

    __syncthreads();
    fft1024_r<-1>(bA, bB, z, tid);

    #pragma unroll
    for (int e = 0; e < 4; e++)
        bA[SWZ(tid + (e << 8))] = make_float2(z[e].r, z[e].i);
    __syncthreads();

    float2* Po = (float2*)(P + (size_t)token * CCH);
    for (int bin = tid; bin < NBINS; bin += 256) {
        float2 Zb = bA[SWZ(bin)];
        float2 Zm = bA[SWZ((1024 - bin) & 1023)];
        float ar = 0.5f * (Zb.x + Zm.x);
        float ai = 0.5f * (Zb.y - Zm.y);
        float br = 0.5f * (Zb.y + Zm.y);
        float bi = 0.5f * (Zm.x - Zb.x);
        Po[bin] = make_float2(ar * br - ai * bi, ar * bi + ai * br);
    }
}

// ---------------------------------------------------------------------------
// Cumsum pass 1: in-place local cumsum within each t-chunk + chunk totals.
// ---------------------------------------------------------------------------
__global__ __launch_bounds__(256) void cumsum_local(
        float* __restrict__ S, float* __restrict__ totals) {
    const int c = blockIdx.x * 256 + threadIdx.x;
    if (c >= CCH) return;
    const int chunk = blockIdx.y;
    const int b = blockIdx.z;
    size_t p = ((size_t)b * L_SZ + (size_t)chunk * TLEN) * CCH + c;
    float acc = 0.0f;
    #pragma unroll 4
    for (int t = 0; t < TLEN; t++) {
        acc += S[p];
        S[p] = acc;
        p += CCH;
    }
    totals[((size_t)b * TCH + chunk) * CCH + c] = acc;
}

// Pass 2: turn chunk totals into EXCLUSIVE prefix offsets (in place).
__global__ __launch_bounds__(256) void scan_totals(float* __restrict__ totals) {
    const int c = blockIdx.x * 256 + threadIdx.x;
    if (c >= CCH) return;
    const int b = blockIdx.y;
    float acc = 0.0f;
    for (int ch = 0; ch < TCH; ch++) {
        size_t idx = ((size_t)b * TCH + ch) * CCH + c;
        float v = totals[idx];
        totals[idx] = acc;
        acc += v;
    }
}

// ---------------------------------------------------------------------------
// Unbind: recompute normalized-key FFT, Rf = (S_local+off)*conj(Kf),
// Hermitian extend, inverse FFT, /sqrt(t+1), LayerNorm -> bf16 RLN.
// ---------------------------------------------------------------------------
__global__ __launch_bounds__(256) void unbind_ln_kernel(
        const float* __restrict__ P, const float* __restrict__ totals,
        const float* __restrict__ Kraw,
        const float* __restrict__ ln_g, const float* __restrict__ ln_b,
        unsigned short* __restrict__ RLNb) {
    __shared__ float2 bA[1024], bB[1024];
    __shared__ float red1[256], red2[256];
    const int token = blockIdx.x;
    const int tid = threadIdx.x;
    const int b = token >> 12;
    const int t = token & (L_SZ - 1);
    const int chunk = t >> 7;

    const float* krow = Kraw + (size_t)token * D_SZ;
    float kv[4];
    float ss = 0.0f;
    #pragma unroll
    for (int k = 0; k < 4; k++) {
        kv[k] = krow[tid + (k << 8)];
        ss += kv[k] * kv[k];
    }
    red1[tid] = ss;
    __syncthreads();
    for (int sft = 128; sft > 0; sft >>= 1) {
        if (tid < sft) red1[tid] += red1[tid + sft];
        __syncthreads();
    }
    const float scale = 1.0f / fmaxf(sqrtf(red1[0]), 1e-12f);

    cplx kz[4];
    #pragma unroll
    for (int k = 0; k < 4; k++) kz[k] = {kv[k] * scale, 0.0f};

    __syncthreads();
    fft1024_r<-1>(bA, bB, kz, tid);     // kz[e] = Kf[tid + 256e]

    const float2* Srow   = (const float2*)(P + (size_t)token * CCH);
    const float2* offrow = (const float2*)(totals + ((size_t)b * TCH + chunk) * CCH);
    #pragma unroll
    for (int e = 0; e < 3; e++) {
        const int bin = tid + (e << 8);
        if (bin < NBINS) {
            float2 s2 = Srow[bin];
            float2 o2 = offrow[bin];
            float sr = s2.x + o2.x, si = s2.y + o2.y;
            float kr = kz[e].r, ki = kz[e].i;
            bA[SWZ(bin)] = make_float2(sr * kr + si * ki, si * kr - sr * ki);
        }
    }
    __syncthreads();
    for (int n = 513 + tid; n < 1024; n += 256) {
        float2 c = bA[SWZ(1024 - n)];
        bA[SWZ(n)] = make_float2(c.x, -c.y);
    }
    __syncthreads();

    cplx rz[4];
    #pragma unroll
    for (int k = 0; k < 4; k++) {
        float2 c = bA[SWZ(tid + (k << 8))];
        rz[k] = {c.x, c.y};
    }
    __syncthreads();
    fft1024_r<1>(bA, bB, rz, tid);      // rz[e].r = r[tid + 256e] * 1024

    const float posscale = (1.0f / 1024.0f) * rsqrtf((float)(t + 1));
    float rv[4];
    float sum = 0.0f, sumsq = 0.0f;
    #pragma unroll
    for (int e = 0; e < 4; e++) {
        float v = rz[e].r * posscale;
        rv[e] = v;
        sum += v;
        sumsq += v * v;
    }
    red1[tid] = sum; red2[tid] = sumsq;
    __syncthreads();
    for (int sft = 128; sft > 0; sft >>= 1) {
        if (tid < sft) { red1[tid] += red1[tid + sft]; red2[tid] += red2[tid + sft]; }
        __syncthreads();
    }
    const float mu = red1[0] * (1.0f / 1024.0f);
    const float var = red2[0] * (1.0f / 1024.0f) - mu * mu;
    const float rstd = rsqrtf(var + 1e-5f);

    unsigned short* outp = RLNb + (size_t)token * D_SZ;
    #pragma unroll
    for (int e = 0; e < 4; e++) {
        const int d = tid + (e << 8);
        outp[d] = f2bf((rv[e] - mu) * rstd * ln_g[d] + ln_b[d]);
    }
}

// ---------------------------------------------------------------------------
// Workspace (bytes):
//   Kraw   fp32 M*D    = 64.0 MB
//   V      fp32 M*D    = 64.0 MB  (dead after bind; reused as bf16 RLN)
//   P      fp32 M*CCH  = 67.2 MB  (local cumsum in place)
//   totals fp32        =  0.5 MB
//   xb     bf16 M*D    = 32.0 MB
//   WB     bf16 2048*D =  4.0 MB  (Wk ++ Wv, concatenated)
//   Wob    bf16 D*D    =  2.0 MB
//   total ~= 234 MB
// ---------------------------------------------------------------------------
extern "C" void kernel_launch(void* const* d_in, const int* in_sizes, int n_in,
                              void* d_out, int out_size, void* d_ws, size_t ws_size,
                              hipStream_t stream) {
    (void)in_sizes; (void)n_in; (void)out_size; (void)ws_size;
    const float* x    = (const float*)d_in[0];
    const float* Wk   = (const float*)d_in[1];
    const float* bk   = (const float*)d_in[2];
    const float* Wv   = (const float*)d_in[3];
    const float* bv   = (const float*)d_in[4];
    const float* ln_g = (const float*)d_in[5];
    const float* ln_b = (const float*)d_in[6];
    const float* Wo   = (const float*)d_in[7];
    const float* bo   = (const float*)d_in[8];
    float* out = (float*)d_out;

    char* w = (char*)d_ws;
    float* Kraw   = (float*)w;  w += (size_t)M_SZ * D_SZ * 4;
    float* V      = (float*)w;  w += (size_t)M_SZ * D_SZ * 4;
    float* P      = (float*)w;  w += (size_t)M_SZ * CCH * 4;
    float* totals = (float*)w;  w += (size_t)B_SZ * TCH * CCH * 4;
    unsigned short* xb  = (unsigned short*)w;  w += (size_t)M_SZ * D_SZ * 2;
    unsigned short* WB  = (unsigned short*)w;  w += (size_t)2 * D_SZ * D_SZ * 2;
    unsigned short* Wob = (unsigned short*)w;  w += (size_t)D_SZ * D_SZ * 2;
    unsigned short* RLNb = (unsigned short*)V;  // overlays dead V

    const int n8x = M_SZ * D_SZ / 8;
    const int n8w = D_SZ * D_SZ / 8;
    cast_f32_bf16<<<n8x / 256, 256, 0, stream>>>(x,  xb,  n8x);
    cast_f32_bf16<<<n8w / 256, 256, 0, stream>>>(Wk, WB,                  n8w);
    cast_f32_bf16<<<n8w / 256, 256, 0, stream>>>(Wv, WB + D_SZ * D_SZ,    n8w);
    cast_f32_bf16<<<n8w / 256, 256, 0, stream>>>(Wo, Wob, n8w);

    // fused K/V projection: N=2048 (first half -> Kraw, second -> V)
    gemm_mfma<16><<<(M_SZ / GBM) * 16, 256, 0, stream>>>(
        xb, WB, bk, bv, nullptr, Kraw, V, M_SZ, D_SZ);

    bind_fft_kernel<<<M_SZ, 256, 0, stream>>>(Kraw, V, P);

    dim3 cgrid((CCH + 255) / 256, TCH, B_SZ);
    cumsum_local<<<cgrid, 256, 0, stream>>>(P, totals);
    dim3 sgrid((CCH + 255) / 256, B_SZ);
    scan_totals<<<sgrid, 256, 0, stream>>>(totals);

    unbind_ln_kernel<<<M_SZ, 256, 0, stream>>>(P, totals, Kraw, ln_g, ln_b, RLNb);

    // output GEMM with fp32 residual
    gemm_mfma<8><<<(M_SZ / GBM) * 8, 256, 0, stream>>>(
        RLNb, Wob, bo, bo, x, out, out, M_SZ, D_SZ);
}